// Round 7
// baseline (579.377 us; speedup 1.0000x reference)
//
#include <hip/hip_runtime.h>

#define M_DIM 65536
#define K_DIM 2048
#define N_DIM 1024
#define EPSV 1e-5f

typedef __bf16 bf16;
typedef bf16 bf16x8 __attribute__((ext_vector_type(8)));
typedef bf16 bf16x4 __attribute__((ext_vector_type(4)));
typedef float f32x4 __attribute__((ext_vector_type(4)));

// monotone float <-> uint encoding for atomicMin on float
__device__ inline unsigned fenc(float f) {
    unsigned u = __float_as_uint(f);
    return (u & 0x80000000u) ? ~u : (u | 0x80000000u);
}
__device__ inline float fdec(unsigned e) {
    unsigned u = (e & 0x80000000u) ? (e & 0x7fffffffu) : ~e;
    return __uint_as_float(u);
}

__device__ __forceinline__ void gload_lds16(const bf16* g, bf16* l) {
    __builtin_amdgcn_global_load_lds(
        (const __attribute__((address_space(1))) unsigned int*)g,
        (__attribute__((address_space(3))) unsigned int*)l, 16, 0, 0);
}

// fp32 -> bf16 conversion, vectorized
__global__ void cvt_kernel(const float* __restrict__ in, bf16* __restrict__ out, long n4) {
    long i = (long)blockIdx.x * blockDim.x + threadIdx.x;
    long stride = (long)gridDim.x * blockDim.x;
    for (; i < n4; i += stride) {
        float4 v = ((const float4*)in)[i];
        bf16x4 h;
        h[0] = (bf16)v.x; h[1] = (bf16)v.y; h[2] = (bf16)v.z; h[3] = (bf16)v.w;
        ((bf16x4*)out)[i] = h;
    }
}

// Stage one [128 rows][32 k] bf16 half-tile (8 KB): 256 threads x 2
// global_load_lds(16B). LDS dest LINEAR (wave-uniform base + lane*16);
// XOR swizzle (granule ^= (row>>1)&3) applied to the GLOBAL source
// (both-sides involution, rule 21). Conflict-free pattern proven R2 (=0).
__device__ __forceinline__ void stage_half(const bf16* __restrict__ g0, int kbase,
                                           bf16* slot, int tid) {
#pragma unroll
    for (int i = 0; i < 2; ++i) {
        int gidx = i * 256 + tid;           // 16B granule id, 512 per half-tile
        int row = gidx >> 2;                // 4 granules (64B) per row, rows 0..127
        int gsw = (gidx & 3) ^ ((row >> 1) & 3);
        gload_lds16(g0 + (size_t)row * K_DIM + kbase + gsw * 8,
                    slot + (size_t)(i * 256 + (tid & 192)) * 8);  // wave-uniform base
    }
}

// LDS slots: A[parity][khalf], B[parity][khalf], each [128][32] bf16 = 8KB.
// Total 64 KiB -> 2 blocks/CU (the point of this round: cross-block overlap).
#define ASL(P, H) (lds + ((P) * 2 + (H)) * 4096)
#define BSL(P, H) (lds + 16384 + ((P) * 2 + (H)) * 4096)

// 128x128 tile, BK=64 as two K-halves of 32; 4 waves (2Mx2N), per-wave 64x64
// (4x4 frags of 16x16x32). 4 phases per iteration (2 K-tiles); each phase:
// [counted-vmcnt gate at Q0/Q2] 8 ds_read_b128 -> stage 1 A+B half-tile ->
// barrier / setprio / 16 MFMA / setprio / barrier. Two independent blocks
// per CU provide the MFMA<->LDS overlap that intra-block scheduling could
// not (R2/R4/R6 all ~1580 cyc/phase). Ring safety: each slot's reads are
// lgkm-complete before its phase's close barrier (reads consumed same
// phase), and restaging issues only after that barrier; vmcnt(4) gates
// wait on loads issued 3-4 phases earlier.
__global__ __launch_bounds__(256, 2)
void gemm_fused(const bf16* __restrict__ Xb, const bf16* __restrict__ Wb,
                const float* __restrict__ gnw, const float* __restrict__ gnb,
                unsigned* __restrict__ rowmin) {
    extern __shared__ __align__(16) bf16 lds[];  // 64 KiB dynamic

    const int tid = threadIdx.x;
    const int wave = tid >> 6, lane = tid & 63;
    const int wr = wave >> 1, wc = wave & 1;     // 2 x 2 wave grid
    const int q = lane >> 4, r = lane & 15;

    // T1: bijective XCD-chunked block swizzle (4096 blocks % 8 == 0).
    // Chunk of 512 consecutive swz per XCD = 64 by x 8 bx -> A-panel reuse in L2.
    const int bid = blockIdx.x;
    const int swz = (bid & 7) * 512 + (bid >> 3);
    const int bx = swz & 7, by = swz >> 3;
    const int brow = by * 128, bcol = bx * 128;

    const bf16* Arow = Xb + (size_t)brow * K_DIM;
    const bf16* Brow = Wb + (size_t)bcol * K_DIM;

    // per-lane LDS read offsets (bf16 units); swizzle term (row>>1)&3 == (r>>1)&3
    const int gswr = (r >> 1) & 3;
    const int aoff = (wr * 64 + r) * 32 + (q ^ gswr) * 8;
    const int boff = (wc * 64 + r) * 32 + (q ^ gswr) * 8;

    f32x4 acc[4][4];
#pragma unroll
    for (int m = 0; m < 4; ++m)
#pragma unroll
        for (int n = 0; n < 4; ++n) acc[m][n] = 0.0f;

    bf16x8 af[4], bfr[4];

#define VMSYNC do {                                              \
        asm volatile("s_waitcnt vmcnt(4)" ::: "memory");          \
        __builtin_amdgcn_s_barrier();                             \
        asm volatile("" ::: "memory");                            \
    } while (0)

#define READ(P, H) {                                                              \
        _Pragma("unroll") for (int m = 0; m < 4; ++m)                             \
            af[m] = *(const bf16x8*)(ASL(P, H) + aoff + m * 512);                 \
        _Pragma("unroll") for (int n = 0; n < 4; ++n)                             \
            bfr[n] = *(const bf16x8*)(BSL(P, H) + boff + n * 512);                \
    }

#define MFMA_PH() do {                                                            \
        __builtin_amdgcn_s_barrier();                                             \
        __builtin_amdgcn_s_setprio(1);                                            \
        _Pragma("unroll") for (int m = 0; m < 4; ++m)                             \
            _Pragma("unroll") for (int n = 0; n < 4; ++n)                         \
                acc[m][n] = __builtin_amdgcn_mfma_f32_16x16x32_bf16(              \
                    af[m], bfr[n], acc[m][n], 0, 0, 0);                           \
        __builtin_amdgcn_s_setprio(0);                                            \
        __builtin_amdgcn_s_barrier();                                             \
    } while (0)

    // ---- prologue: stage (0,0),(0,1),(1,0) A+B = 12 loads/thread ----
    stage_half(Arow, 0,  ASL(0, 0), tid);
    stage_half(Brow, 0,  BSL(0, 0), tid);
    stage_half(Arow, 32, ASL(0, 1), tid);
    stage_half(Brow, 32, BSL(0, 1), tid);
    stage_half(Arow, 64, ASL(1, 0), tid);
    stage_half(Brow, 64, BSL(1, 0), tid);

    // ---- main loop: 16 iterations x 2 K-tiles (K=2048, BK=64) ----
    for (int i = 0; i < 16; ++i) {
        const int tb = 2 * i + 1;
        const int t2 = (2 * i + 2) & 31, t3 = (2 * i + 3) & 31;  // wrap: staged, never read
        // Q0: gate (drains (0,0)+(0,1) stagers); consume (0,0); stage (2i+1)h1
        VMSYNC;
        READ(0, 0);
        stage_half(Arow, tb * 64 + 32, ASL(1, 1), tid);
        stage_half(Brow, tb * 64 + 32, BSL(1, 1), tid);
        MFMA_PH();
        // Q1: consume (0,1); stage (2i+2)h0
        READ(0, 1);
        stage_half(Arow, t2 * 64, ASL(0, 0), tid);
        stage_half(Brow, t2 * 64, BSL(0, 0), tid);
        MFMA_PH();
        // Q2: gate (drains (1,0)+(1,1) stagers); consume (1,0); stage (2i+2)h1
        VMSYNC;
        READ(1, 0);
        stage_half(Arow, t2 * 64 + 32, ASL(0, 1), tid);
        stage_half(Brow, t2 * 64 + 32, BSL(0, 1), tid);
        MFMA_PH();
        // Q3: consume (1,1); stage (2i+3)h0
        READ(1, 1);
        stage_half(Arow, t3 * 64, ASL(1, 0), tid);
        stage_half(Brow, t3 * 64, BSL(1, 0), tid);
        MFMA_PH();
    }

    // ---- fused epilogue: GroupNorm (group == wave's 64-col span) + row min ----
    float gw[4], gb[4];
#pragma unroll
    for (int n = 0; n < 4; ++n) {
        int col = bcol + wc * 64 + n * 16 + r;
        gw[n] = gnw[col];
        gb[n] = gnb[col];
    }
#pragma unroll
    for (int m = 0; m < 4; ++m) {
#pragma unroll
        for (int j = 0; j < 4; ++j) {
            float s = 0.f, ss = 0.f;
#pragma unroll
            for (int n = 0; n < 4; ++n) {
                float v = acc[m][n][j];
                s += v; ss += v * v;
            }
#pragma unroll
            for (int d = 1; d < 16; d <<= 1) {
                s += __shfl_xor(s, d);
                ss += __shfl_xor(ss, d);
            }
            float mean = s * (1.f / 64.f);
            float var = ss * (1.f / 64.f) - mean * mean;
            float rstd = rsqrtf(var + EPSV);
            float mn = 3.4e38f;
#pragma unroll
            for (int n = 0; n < 4; ++n) {
                float y = (acc[m][n][j] - mean) * rstd * gw[n] + gb[n];
                mn = fminf(mn, y);
            }
#pragma unroll
            for (int d = 1; d < 16; d <<= 1) mn = fminf(mn, __shfl_xor(mn, d));
            if (r == 0)
                atomicMin(&rowmin[brow + wr * 64 + m * 16 + q * 4 + j], fenc(mn));
        }
    }
}

// out[m][n] = dec(rowmin[m]) + bias[n]
__global__ void bcast_kernel(const unsigned* __restrict__ rowmin,
                             const float* __restrict__ bias,
                             float* __restrict__ out) {
    const long total4 = (long)M_DIM * N_DIM / 4;
    long i = (long)blockIdx.x * blockDim.x + threadIdx.x;
    long stride = (long)gridDim.x * blockDim.x;
    for (; i < total4; i += stride) {
        int mrow = (int)(i >> 8);  // N/4 = 256 float4 per row
        int n4 = (int)(i & 255);
        float rm = fdec(rowmin[mrow]);
        float4 b = ((const float4*)bias)[n4];
        float4 o;
        o.x = rm + b.x; o.y = rm + b.y; o.z = rm + b.z; o.w = rm + b.w;
        ((float4*)out)[i] = o;
    }
}

extern "C" void kernel_launch(void* const* d_in, const int* in_sizes, int n_in,
                              void* d_out, int out_size, void* d_ws, size_t ws_size,
                              hipStream_t stream) {
    const float* x = (const float*)d_in[0];
    const float* w = (const float*)d_in[1];
    const float* gnw = (const float*)d_in[2];
    const float* gnb = (const float*)d_in[3];
    const float* bias = (const float*)d_in[4];

    unsigned char* ws = (unsigned char*)d_ws;
    unsigned* rowmin = (unsigned*)ws;                          // 256 KB
    bf16* wb = (bf16*)(ws + (size_t)M_DIM * 4);                // 4 MB
    bf16* xb = (bf16*)(ws + (size_t)M_DIM * 4 + (size_t)N_DIM * K_DIM * 2);  // 256 MB

    hipFuncSetAttribute((const void*)gemm_fused,
                        hipFuncAttributeMaxDynamicSharedMemorySize, 65536);

    hipMemsetAsync(rowmin, 0xFF, (size_t)M_DIM * 4, stream);   // +inf in encoding
    cvt_kernel<<<512, 256, 0, stream>>>(w, wb, (long)N_DIM * K_DIM / 4);
    cvt_kernel<<<4096, 256, 0, stream>>>(x, xb, (long)M_DIM * K_DIM / 4);

    gemm_fused<<<dim3(4096), 256, 65536, stream>>>(xb, wb, gnw, gnb, rowmin);

    bcast_kernel<<<2048, 256, 0, stream>>>(rowmin, bias, (float*)d_out);
}

// Round 9
// 519.376 us; speedup vs baseline: 1.1155x; 1.1155x over previous
//
#include <hip/hip_runtime.h>

#define M_DIM 65536
#define K_DIM 2048
#define N_DIM 1024
#define EPSV 1e-5f

typedef __bf16 bf16;
typedef bf16 bf16x8 __attribute__((ext_vector_type(8)));
typedef bf16 bf16x4 __attribute__((ext_vector_type(4)));
typedef float f32x4 __attribute__((ext_vector_type(4)));

// monotone float <-> uint encoding for atomicMin on float
__device__ inline unsigned fenc(float f) {
    unsigned u = __float_as_uint(f);
    return (u & 0x80000000u) ? ~u : (u | 0x80000000u);
}
__device__ inline float fdec(unsigned e) {
    unsigned u = (e & 0x80000000u) ? (e & 0x7fffffffu) : ~e;
    return __uint_as_float(u);
}

__device__ __forceinline__ void gload_lds16(const bf16* g, bf16* l) {
    __builtin_amdgcn_global_load_lds(
        (const __attribute__((address_space(1))) unsigned int*)g,
        (__attribute__((address_space(3))) unsigned int*)l, 16, 0, 0);
}

// fp32 -> bf16 conversion, vectorized
__global__ void cvt_kernel(const float* __restrict__ in, bf16* __restrict__ out, long n4) {
    long i = (long)blockIdx.x * blockDim.x + threadIdx.x;
    long stride = (long)gridDim.x * blockDim.x;
    for (; i < n4; i += stride) {
        float4 v = ((const float4*)in)[i];
        bf16x4 h;
        h[0] = (bf16)v.x; h[1] = (bf16)v.y; h[2] = (bf16)v.z; h[3] = (bf16)v.w;
        ((bf16x4*)out)[i] = h;
    }
}

// Stage one [256 rows][32 k] bf16 half-tile (16 KB): 512 threads x 2
// global_load_lds(16B). LDS dest LINEAR; XOR swizzle (granule ^= (row>>1)&3)
// applied to the GLOBAL source (both-sides involution). Conflict-free (R2: 0).
__device__ __forceinline__ void stage_half(const bf16* __restrict__ g0, int kbase,
                                           bf16* slot, int tid) {
#pragma unroll
    for (int i = 0; i < 2; ++i) {
        int gidx = i * 512 + tid;           // 16B granule id, 1024 per half-tile
        int row = gidx >> 2;                // 4 granules (64B) per row
        int gsw = (gidx & 3) ^ ((row >> 1) & 3);
        gload_lds16(g0 + (size_t)row * K_DIM + kbase + gsw * 8,
                    slot + (size_t)(i * 512 + (tid & 448)) * 8);  // wave-uniform base
    }
}

// LDS slots: A[parity][khalf], B[parity][khalf], each [256][32] bf16 = 16KB.
#define ASL(P, H) (lds + ((P) * 2 + (H)) * 8192)
#define BSL(P, H) (lds + 32768 + ((P) * 2 + (H)) * 8192)

// 256x256 tile, BK=64 as two K-halves of 32; 8 waves (2Mx4N), per-wave 128x64
// (8x4 frags of 16x16x32). FAT PHASES: 4 per iteration (2 K-tiles), each =
// 12 ds_read_b128 (A mh0 + A mh1 + B) + 1 half-tile stage (A+B) + barrier /
// setprio / 32 MFMA / setprio / barrier. Halves the barrier count vs R4's
// 8 thin phases. Gates VMSYNC(4) at Q0/Q2 drain TWO half-tile batches each
// (R8 bug: vmcnt(8) drained one -> race; R4's working depth was 4).
// Queue replay (steady state, 4 loads/batch):
//   Q0 entry [a.h0,a.h1,b.h0]=12 -> vmcnt(4) drains a.h0+a.h1; R(a.h0),
//   Q1 R(a.h1) both safe; stages push b.h1, a'.h0.
//   Q2 entry [b.h0,b.h1,a'.h0]=12 -> vmcnt(4) drains b.h0+b.h1; R safe.
// R8 bug #2 fixed: mh1 A-frag offset is (4+m)*512 (+64 rows), was (16+m).
__global__ __launch_bounds__(512, 2)
void gemm_fused(const bf16* __restrict__ Xb, const bf16* __restrict__ Wb,
                const float* __restrict__ gnw, const float* __restrict__ gnb,
                unsigned* __restrict__ rowmin) {
    extern __shared__ __align__(16) bf16 lds[];  // 128 KiB dynamic

    const int tid = threadIdx.x;
    const int wave = tid >> 6, lane = tid & 63;
    const int wr = wave >> 2, wc = wave & 3;     // 2 x 4 wave grid
    const int q = lane >> 4, r = lane & 15;

    // T1: bijective XCD-chunked block swizzle (1024 blocks % 8 == 0)
    const int bid = blockIdx.x;
    const int swz = (bid & 7) * 128 + (bid >> 3);
    const int bx = swz & 3, by = swz >> 2;
    const int brow = by * 256, bcol = bx * 256;

    const bf16* Arow = Xb + (size_t)brow * K_DIM;
    const bf16* Brow = Wb + (size_t)bcol * K_DIM;

    // per-lane LDS read offsets (bf16 units); swizzle term (row>>1)&3 == (r>>1)&3
    // (all A-frag rows r+16k share it: 16k is 0 mod 4 after >>1)
    const int gswr = (r >> 1) & 3;
    const int aoff = (wr * 128 + r) * 32 + (q ^ gswr) * 8;
    const int boff = (wc * 64 + r) * 32 + (q ^ gswr) * 8;

    f32x4 acc[8][4];
#pragma unroll
    for (int m = 0; m < 8; ++m)
#pragma unroll
        for (int n = 0; n < 4; ++n) acc[m][n] = 0.0f;

    bf16x8 af0[4], af1[4], bfr[4];

#define VMSYNC(N) do {                                           \
        asm volatile("s_waitcnt vmcnt(" #N ")" ::: "memory");     \
        __builtin_amdgcn_s_barrier();                             \
        asm volatile("" ::: "memory");                            \
    } while (0)

    // 12 ds_read_b128: A rows m*16 (mh0) and 64+m*16 (mh1) + B cols
#define READ12(P, H) {                                                            \
        _Pragma("unroll") for (int m = 0; m < 4; ++m)                             \
            af0[m] = *(const bf16x8*)(ASL(P, H) + aoff + m * 512);                \
        _Pragma("unroll") for (int m = 0; m < 4; ++m)                             \
            af1[m] = *(const bf16x8*)(ASL(P, H) + aoff + (4 + m) * 512);          \
        _Pragma("unroll") for (int n = 0; n < 4; ++n)                             \
            bfr[n] = *(const bf16x8*)(BSL(P, H) + boff + n * 512);                \
    }

    // fat cluster: 32 MFMA (mh0 x 16, mh1 x 16); compiler inserts the
    // fine-grained lgkmcnt waits (R4-proven equivalent to manual pin)
#define MFMA_FAT() do {                                                           \
        __builtin_amdgcn_s_barrier();                                             \
        __builtin_amdgcn_s_setprio(1);                                            \
        _Pragma("unroll") for (int m = 0; m < 4; ++m)                             \
            _Pragma("unroll") for (int n = 0; n < 4; ++n)                         \
                acc[m][n] = __builtin_amdgcn_mfma_f32_16x16x32_bf16(              \
                    af0[m], bfr[n], acc[m][n], 0, 0, 0);                          \
        _Pragma("unroll") for (int m = 0; m < 4; ++m)                             \
            _Pragma("unroll") for (int n = 0; n < 4; ++n)                         \
                acc[4 + m][n] = __builtin_amdgcn_mfma_f32_16x16x32_bf16(          \
                    af1[m], bfr[n], acc[4 + m][n], 0, 0, 0);                      \
        __builtin_amdgcn_s_setprio(0);                                            \
        __builtin_amdgcn_s_barrier();                                             \
    } while (0)

    // ---- prologue: stage t0h0, t0h1, t1h0 (A+B each) = 12 loads/thread;
    // drain t0 (8 oldest) with vmcnt(4)+barrier.
    stage_half(Arow, 0,  ASL(0, 0), tid);
    stage_half(Brow, 0,  BSL(0, 0), tid);
    stage_half(Arow, 32, ASL(0, 1), tid);
    stage_half(Brow, 32, BSL(0, 1), tid);
    stage_half(Arow, 64, ASL(1, 0), tid);
    stage_half(Brow, 64, BSL(1, 0), tid);
    asm volatile("s_waitcnt vmcnt(4)" ::: "memory");
    __builtin_amdgcn_s_barrier();

    // ---- main loop: 16 iterations x 2 K-tiles (K=2048, BK=64) ----
    for (int i = 0; i < 16; ++i) {
        const int tb = 2 * i + 1;
        const int t2 = (2 * i + 2) & 31, t3 = (2 * i + 3) & 31;  // wrap: staged, never read
        // Q0: gate (drains a.h0+a.h1); consume (0,0); stage (2i+1)h1
        VMSYNC(4);
        READ12(0, 0);
        stage_half(Arow, tb * 64 + 32, ASL(1, 1), tid);
        stage_half(Brow, tb * 64 + 32, BSL(1, 1), tid);
        MFMA_FAT();
        // Q1: consume (0,1); stage (2i+2)h0
        READ12(0, 1);
        stage_half(Arow, t2 * 64, ASL(0, 0), tid);
        stage_half(Brow, t2 * 64, BSL(0, 0), tid);
        MFMA_FAT();
        // Q2: gate (drains b.h0+b.h1); consume (1,0); stage (2i+2)h1
        VMSYNC(4);
        READ12(1, 0);
        stage_half(Arow, t2 * 64 + 32, ASL(0, 1), tid);
        stage_half(Brow, t2 * 64 + 32, BSL(0, 1), tid);
        MFMA_FAT();
        // Q3: consume (1,1); stage (2i+3)h0
        READ12(1, 1);
        stage_half(Arow, t3 * 64, ASL(1, 0), tid);
        stage_half(Brow, t3 * 64, BSL(1, 0), tid);
        MFMA_FAT();
    }

    // ---- fused epilogue: GroupNorm (group == wave's 64-col span) + row min ----
    float gw[4], gb[4];
#pragma unroll
    for (int n = 0; n < 4; ++n) {
        int col = bcol + wc * 64 + n * 16 + r;
        gw[n] = gnw[col];
        gb[n] = gnb[col];
    }
#pragma unroll
    for (int m = 0; m < 8; ++m) {
#pragma unroll
        for (int j = 0; j < 4; ++j) {
            float s = 0.f, ss = 0.f;
#pragma unroll
            for (int n = 0; n < 4; ++n) {
                float v = acc[m][n][j];
                s += v; ss += v * v;
            }
#pragma unroll
            for (int d = 1; d < 16; d <<= 1) {
                s += __shfl_xor(s, d);
                ss += __shfl_xor(ss, d);
            }
            float mean = s * (1.f / 64.f);
            float var = ss * (1.f / 64.f) - mean * mean;
            float rstd = rsqrtf(var + EPSV);
            float mn = 3.4e38f;
#pragma unroll
            for (int n = 0; n < 4; ++n) {
                float y = (acc[m][n][j] - mean) * rstd * gw[n] + gb[n];
                mn = fminf(mn, y);
            }
#pragma unroll
            for (int d = 1; d < 16; d <<= 1) mn = fminf(mn, __shfl_xor(mn, d));
            if (r == 0)
                atomicMin(&rowmin[brow + wr * 128 + m * 16 + q * 4 + j], fenc(mn));
        }
    }
}

// out[m][n] = dec(rowmin[m]) + bias[n]
__global__ void bcast_kernel(const unsigned* __restrict__ rowmin,
                             const float* __restrict__ bias,
                             float* __restrict__ out) {
    const long total4 = (long)M_DIM * N_DIM / 4;
    long i = (long)blockIdx.x * blockDim.x + threadIdx.x;
    long stride = (long)gridDim.x * blockDim.x;
    for (; i < total4; i += stride) {
        int mrow = (int)(i >> 8);  // N/4 = 256 float4 per row
        int n4 = (int)(i & 255);
        float rm = fdec(rowmin[mrow]);
        float4 b = ((const float4*)bias)[n4];
        float4 o;
        o.x = rm + b.x; o.y = rm + b.y; o.z = rm + b.z; o.w = rm + b.w;
        ((float4*)out)[i] = o;
    }
}

extern "C" void kernel_launch(void* const* d_in, const int* in_sizes, int n_in,
                              void* d_out, int out_size, void* d_ws, size_t ws_size,
                              hipStream_t stream) {
    const float* x = (const float*)d_in[0];
    const float* w = (const float*)d_in[1];
    const float* gnw = (const float*)d_in[2];
    const float* gnb = (const float*)d_in[3];
    const float* bias = (const float*)d_in[4];

    unsigned char* ws = (unsigned char*)d_ws;
    unsigned* rowmin = (unsigned*)ws;                          // 256 KB
    bf16* wb = (bf16*)(ws + (size_t)M_DIM * 4);                // 4 MB
    bf16* xb = (bf16*)(ws + (size_t)M_DIM * 4 + (size_t)N_DIM * K_DIM * 2);  // 256 MB

    hipFuncSetAttribute((const void*)gemm_fused,
                        hipFuncAttributeMaxDynamicSharedMemorySize, 131072);

    hipMemsetAsync(rowmin, 0xFF, (size_t)M_DIM * 4, stream);   // +inf in encoding
    cvt_kernel<<<512, 256, 0, stream>>>(w, wb, (long)N_DIM * K_DIM / 4);
    cvt_kernel<<<4096, 256, 0, stream>>>(x, xb, (long)M_DIM * K_DIM / 4);

    gemm_fused<<<dim3(1024), 512, 131072, stream>>>(xb, wb, gnw, gnb, rowmin);

    bcast_kernel<<<2048, 256, 0, stream>>>(rowmin, bias, (float*)d_out);
}